// Round 2
// baseline (407.749 us; speedup 1.0000x reference)
//
#include <hip/hip_runtime.h>
#include <hip/hip_bf16.h>
#include <cstdint>

#define B_  16
#define TP  4096
#define TQ  512
#define D2_ 256

#define TI 64
#define TJ 64
#define NJT (TQ / TJ)   // 8
#define UPITCH 258      // f16; 129 dwords (odd) per row
#define UTPITCH 66      // f16; 33 dwords (odd)
#define PPITCH 66

typedef _Float16 f16x8 __attribute__((ext_vector_type(8)));
typedef _Float16 f16x4 __attribute__((ext_vector_type(4)));
typedef float    f32x4 __attribute__((ext_vector_type(4)));

// ---- scratch stashed in d_out slice-3 region (overwritten by k_g3 at the end) ----
// Uf16  logical [b][j][c]  -> G rows 0..4095   (batch 0 slice-3)
// Utf16 logical [b][c][j]  -> G rows 4096..8191 (batch 1 slice-3)
__device__ __forceinline__ _Float16* uf16_ptr(float* G, int b, int j, int c) {
  int r = (b * TQ + j) >> 1;
  return (_Float16*)G + (size_t)r * 2048 + 1536 + (j & 1) * 256 + c;
}
__device__ __forceinline__ _Float16* utf16_ptr(float* G, int b, int c, int j) {
  return (_Float16*)G + (size_t)(4096 + b * D2_ + c) * 2048 + 1536 + j;
}

// ---------------- kernel 0: convert U -> f16 (both layouts) + udot ----------------
__global__ __launch_bounds__(256) void k_prep(const float* __restrict__ U,
                                              const float* __restrict__ w,
                                              const int* __restrict__ mq,
                                              float* __restrict__ G,
                                              float* __restrict__ udot) {
  __shared__ _Float16 T[TJ][UPITCH];
  const int b = blockIdx.y, jt = blockIdx.x;
  const int tid = threadIdx.x, lane = tid & 63, wv = tid >> 6;

#pragma unroll
  for (int it = 0; it < 16; ++it) {
    int j = it * 4 + wv;
    int c = lane * 4;
    float qmv = (float)mq[b * TQ + jt * TJ + j];
    f32x4 u = *(const f32x4*)&U[((size_t)(b * TQ + jt * TJ + j)) * D2_ + c];
    u.x *= qmv; u.y *= qmv; u.z *= qmv; u.w *= qmv;
    f16x4 v; v[0] = (_Float16)u.x; v[1] = (_Float16)u.y;
    v[2] = (_Float16)u.z; v[3] = (_Float16)u.w;
    *(f16x4*)&T[j][c] = v;
    f32x4 wu = *(const f32x4*)&w[D2_ + c];
    float p = u.x * wu.x + u.y * wu.y + u.z * wu.z + u.w * wu.w;
#pragma unroll
    for (int o = 32; o; o >>= 1) p += __shfl_down(p, o);
    if (lane == 0) udot[b * TQ + jt * TJ + j] = p;
  }
  __syncthreads();

  // Uf16 row-major out: wave wv covers col chunk wv*64..wv*64+63, rows = lane
#pragma unroll
  for (int it = 0; it < 8; ++it) {
    int col = (wv * 8 + it) * 8;
    f16x8 v = *(const f16x8*)&T[lane][col];
    *(f16x8*)uf16_ptr(G, b, jt * TJ + lane, col) = v;
  }
  // Utf16 out: thread tid owns column c = tid
  {
    int c = tid;
    _Float16 colv[64];
#pragma unroll
    for (int j = 0; j < 64; ++j) colv[j] = T[j][c];
#pragma unroll
    for (int k = 0; k < 8; ++k) {
      f16x8 v;
#pragma unroll
      for (int e = 0; e < 8; ++e) v[e] = colv[k * 8 + e];
      *(f16x8*)utf16_ptr(G, b, c, jt * TJ + k * 8) = v;
    }
  }
}

// ---------------- kernel 1: flash S/softmax/PV + G slices 0..2 + Smax ----------------
__global__ __launch_bounds__(256, 2) void k_main(
    const float* __restrict__ H, const float* __restrict__ w,
    const int* __restrict__ mp, const int* __restrict__ mq,
    const float* __restrict__ udot,
    float* __restrict__ SmaxOut, float* __restrict__ G) {

  __shared__ char smem[66816 + 8448 + 512];
  _Float16 (*Usm)[UPITCH]  = (_Float16(*)[UPITCH])smem;            // 64x258 f16 = 33024
  _Float16 (*Utsm)[UTPITCH] = (_Float16(*)[UTPITCH])(smem + 33024); // 256x66 f16 = 33792
  _Float16 (*Psm)[16][PPITCH] = (_Float16(*)[16][PPITCH])(smem + 66816); // 8448
  float* udot_s = (float*)(smem + 66816 + 8448);  // 64
  float* qm_s   = udot_s + 64;                    // 64

  const int b   = blockIdx.y;
  const int i0  = blockIdx.x * TI;
  const int tid = threadIdx.x;
  const int lane = tid & 63;
  const int wv  = tid >> 6;
  const int l15 = lane & 15;
  const int g   = lane >> 4;

  // ---- A fragments (Hm * w_hu) in registers + hdot in registers ----
  const int rowg = i0 + wv * 16 + l15;
  const float* Hrow = H + ((size_t)b * TP + rowg) * D2_;
  const float pmr = (float)mp[b * TP + rowg];
  f16x8 afr[8];
  float hp = 0.f;
#pragma unroll
  for (int ks = 0; ks < 8; ++ks) {
    int c0 = ks * 32 + g * 8;
    f32x4 h0 = *(const f32x4*)&Hrow[c0];
    f32x4 h1 = *(const f32x4*)&Hrow[c0 + 4];
    f32x4 wh0 = *(const f32x4*)&w[c0];
    f32x4 wh1 = *(const f32x4*)&w[c0 + 4];
    f32x4 wu0 = *(const f32x4*)&w[2 * D2_ + c0];
    f32x4 wu1 = *(const f32x4*)&w[2 * D2_ + c0 + 4];
    h0.x *= pmr; h0.y *= pmr; h0.z *= pmr; h0.w *= pmr;
    h1.x *= pmr; h1.y *= pmr; h1.z *= pmr; h1.w *= pmr;
    f16x8 a;
    a[0] = (_Float16)(h0.x * wu0.x); a[1] = (_Float16)(h0.y * wu0.y);
    a[2] = (_Float16)(h0.z * wu0.z); a[3] = (_Float16)(h0.w * wu0.w);
    a[4] = (_Float16)(h1.x * wu1.x); a[5] = (_Float16)(h1.y * wu1.y);
    a[6] = (_Float16)(h1.z * wu1.z); a[7] = (_Float16)(h1.w * wu1.w);
    afr[ks] = a;
    hp += h0.x * wh0.x + h0.y * wh0.y + h0.z * wh0.z + h0.w * wh0.w
        + h1.x * wh1.x + h1.y * wh1.y + h1.z * wh1.z + h1.w * wh1.w;
  }
  hp += __shfl_xor(hp, 16);
  hp += __shfl_xor(hp, 32);          // all lanes: hdot of row (wv*16 + l15)
  float hd[4];
#pragma unroll
  for (int reg = 0; reg < 4; ++reg) hd[reg] = __shfl(hp, g * 4 + reg);

  f32x4 Oacc[16];
#pragma unroll
  for (int n = 0; n < 16; ++n) Oacc[n] = {0.f, 0.f, 0.f, 0.f};
  float m_r[4] = {-1e30f, -1e30f, -1e30f, -1e30f};
  float l_r[4] = {0.f, 0.f, 0.f, 0.f};

  for (int jt = 0; jt < NJT; ++jt) {
    // ---- stage U (row-major) ----
#pragma unroll
    for (int it = 0; it < 8; ++it) {
      int col = (wv * 8 + it) * 8;
      f16x8 v = *(const f16x8*)uf16_ptr(G, b, jt * TJ + lane, col);
      *(f16x8*)&Usm[lane][col] = v;
    }
    // ---- stage Ut ----
#pragma unroll
    for (int it = 0; it < 8; ++it) {
      int r = wv * 64 + lane;
      f16x8 v = *(const f16x8*)utf16_ptr(G, b, r, jt * TJ + it * 8);
      *(f16x8*)&Utsm[r][it * 8] = v;
    }
    if (tid < TJ) {
      udot_s[tid] = udot[b * TQ + jt * TJ + tid];
      qm_s[tid]   = (float)mq[b * TQ + jt * TJ + tid];
    }
    __syncthreads();

    // ---- S tile: 16 rows x 64 cols per wave ----
    f32x4 Sacc[4];
#pragma unroll
    for (int t = 0; t < 4; ++t) Sacc[t] = {0.f, 0.f, 0.f, 0.f};
#pragma unroll
    for (int ks = 0; ks < 8; ++ks) {
#pragma unroll
      for (int t = 0; t < 4; ++t) {
        f16x8 bfr = *(const f16x8*)&Usm[t * 16 + l15][ks * 32 + g * 8];
        Sacc[t] = __builtin_amdgcn_mfma_f32_16x16x32_f16(afr[ks], bfr, Sacc[t], 0, 0, 0);
      }
    }

    // ---- bias + online softmax ----
    float ud[4], qv[4];
#pragma unroll
    for (int t = 0; t < 4; ++t) { ud[t] = udot_s[t * 16 + l15]; qv[t] = qm_s[t * 16 + l15]; }

    float Sv[4][4];
    float tmax[4] = {-1e30f, -1e30f, -1e30f, -1e30f};
#pragma unroll
    for (int t = 0; t < 4; ++t)
#pragma unroll
      for (int reg = 0; reg < 4; ++reg) {
        float v = Sacc[t][reg] + hd[reg] + ud[t];
        Sv[t][reg] = v;
        tmax[reg] = fmaxf(tmax[reg], v);
      }
#pragma unroll
    for (int o = 1; o < 16; o <<= 1)
#pragma unroll
      for (int reg = 0; reg < 4; ++reg)
        tmax[reg] = fmaxf(tmax[reg], __shfl_xor(tmax[reg], o));

    float scale[4], psum[4] = {0.f, 0.f, 0.f, 0.f};
#pragma unroll
    for (int reg = 0; reg < 4; ++reg) {
      float mn = fmaxf(m_r[reg], tmax[reg]);
      scale[reg] = __expf(m_r[reg] - mn);
      m_r[reg] = mn;
      l_r[reg] *= scale[reg];
    }
#pragma unroll
    for (int n = 0; n < 16; ++n)
#pragma unroll
      for (int reg = 0; reg < 4; ++reg)
        Oacc[n][reg] *= scale[reg];

#pragma unroll
    for (int t = 0; t < 4; ++t)
#pragma unroll
      for (int reg = 0; reg < 4; ++reg) {
        float p = qv[t] * __expf(Sv[t][reg] - m_r[reg]);
        psum[reg] += p;
        Psm[wv][g * 4 + reg][t * 16 + l15] = (_Float16)p;
      }
#pragma unroll
    for (int o = 1; o < 16; o <<= 1)
#pragma unroll
      for (int reg = 0; reg < 4; ++reg)
        psum[reg] += __shfl_xor(psum[reg], o);
#pragma unroll
    for (int reg = 0; reg < 4; ++reg) l_r[reg] += psum[reg];

    // ---- PV: Oacc += P(16x64) @ U(64x256) ----
#pragma unroll
    for (int ks = 0; ks < 2; ++ks) {
      f16x8 pf = *(const f16x8*)&Psm[wv][l15][ks * 32 + g * 8];
#pragma unroll
      for (int n = 0; n < 16; ++n) {
        f16x8 uf = *(const f16x8*)&Utsm[n * 16 + l15][ks * 32 + g * 8];
        Oacc[n] = __builtin_amdgcn_mfma_f32_16x16x32_f16(pf, uf, Oacc[n], 0, 0, 0);
      }
    }
    __syncthreads();
  }

  // ---- Smax out (raw row max) ----
  if (l15 == 0) {
#pragma unroll
    for (int reg = 0; reg < 4; ++reg)
      SmaxOut[b * TP + i0 + wv * 16 + g * 4 + reg] = m_r[reg];
  }

  // ---- normalize, park U_att in LDS, coalesced G writes ----
  float* Uatt = (float*)smem;   // [64][260] f32 = 66560 <= 66816
  float inv_l[4];
#pragma unroll
  for (int reg = 0; reg < 4; ++reg) inv_l[reg] = 1.0f / l_r[reg];
#pragma unroll
  for (int n = 0; n < 16; ++n)
#pragma unroll
    for (int reg = 0; reg < 4; ++reg)
      Uatt[(wv * 16 + g * 4 + reg) * 260 + n * 16 + l15] = Oacc[n][reg] * inv_l[reg];
  __syncthreads();

  const int* pmb = mp + b * TP + i0;
#pragma unroll
  for (int it = 0; it < 16; ++it) {
    int idx4 = it * 256 + tid;
    int r = idx4 >> 6;
    int c = (idx4 & 63) * 4;
    float pm = (float)pmb[r];
    f32x4 h = *(const f32x4*)&H[((size_t)b * TP + i0 + r) * D2_ + c];
    h.x *= pm; h.y *= pm; h.z *= pm; h.w *= pm;
    f32x4 u;
    u.x = Uatt[r * 260 + c];     u.y = Uatt[r * 260 + c + 1];
    u.z = Uatt[r * 260 + c + 2]; u.w = Uatt[r * 260 + c + 3];
    size_t ro = ((size_t)b * TP + i0 + r) * (4 * D2_);
    *(f32x4*)&G[ro + c] = h;
    f32x4 up; up.x = u.x * pm; up.y = u.y * pm; up.z = u.z * pm; up.w = u.w * pm;
    *(f32x4*)&G[ro + D2_ + c] = up;
    f32x4 hu; hu.x = h.x * u.x; hu.y = h.y * u.y; hu.z = h.z * u.z; hu.w = h.w * u.w;
    *(f32x4*)&G[ro + 2 * D2_ + c] = hu;
  }
}

// ---------------- kernel 3a: per-batch max & sum-exp over Smax ----------------
__global__ __launch_bounds__(256) void k_smax_reduce(const float* __restrict__ Smax,
    const int* __restrict__ mp, float* __restrict__ Mb, float* __restrict__ Lb) {
  int b = blockIdx.x;
  int tid = threadIdx.x;
  const float* S = Smax + b * TP;
  const int* pm = mp + b * TP;
  __shared__ float redm[4], reds[4];
  float mx = -1e30f;
  for (int i = tid; i < TP; i += 256) mx = fmaxf(mx, S[i]);
#pragma unroll
  for (int o = 32; o; o >>= 1) mx = fmaxf(mx, __shfl_down(mx, o));
  if ((tid & 63) == 0) redm[tid >> 6] = mx;
  __syncthreads();
  mx = fmaxf(fmaxf(redm[0], redm[1]), fmaxf(redm[2], redm[3]));
  float s = 0.f;
  for (int i = tid; i < TP; i += 256) s += pm[i] ? __expf(S[i] - mx) : 0.f;
#pragma unroll
  for (int o = 32; o; o >>= 1) s += __shfl_down(s, o);
  if ((tid & 63) == 0) reds[tid >> 6] = s;
  __syncthreads();
  if (tid == 0) { Mb[b] = mx; Lb[b] = reds[0] + reds[1] + reds[2] + reds[3]; }
}

// ---------------- kernel 3b: partial h_att (deterministic) ----------------
__global__ __launch_bounds__(256) void k_hatt(const float* __restrict__ H,
    const float* __restrict__ Smax, const int* __restrict__ mp,
    const float* __restrict__ Mb, const float* __restrict__ Lb,
    float* __restrict__ partial) {
  int b = blockIdx.y;
  int chunk = blockIdx.x;
  int c = threadIdx.x;
  float mx = Mb[b];
  float inv = 1.0f / Lb[b];
  float acc = 0.f;
  int i0 = chunk * 128;
  for (int ii = 0; ii < 128; ++ii) {
    int i = i0 + ii;
    float sm = Smax[b * TP + i];
    float wgt = mp[b * TP + i] ? __expf(sm - mx) * inv : 0.f;
    acc += wgt * H[((size_t)b * TP + i) * D2_ + c];
  }
  partial[((size_t)b * 32 + chunk) * D2_ + c] = acc;
}

// ---------------- kernel 3c: sum partials -> h_att ----------------
__global__ __launch_bounds__(256) void k_hatt_sum(const float* __restrict__ partial,
                                                  float* __restrict__ hatt) {
  int b = blockIdx.x;
  int c = threadIdx.x;
  float s = 0.f;
#pragma unroll
  for (int k = 0; k < 32; ++k) s += partial[((size_t)b * 32 + k) * D2_ + c];
  hatt[b * D2_ + c] = s;
}

// ---------------- kernel 4: G slice 3 = Hm * h_att ----------------
__global__ __launch_bounds__(256) void k_g3(const float* __restrict__ H,
    const int* __restrict__ mp, const float* __restrict__ hatt,
    float* __restrict__ G) {
  const int total = B_ * TP * (D2_ / 4);
  for (int idx = blockIdx.x * 256 + threadIdx.x; idx < total; idx += gridDim.x * 256) {
    int c4 = idx & 63;
    int i = (idx >> 6) & (TP - 1);
    int b = idx >> 18;
    float pm = (float)mp[b * TP + i];
    f32x4 h = *(const f32x4*)&H[((size_t)b * TP + i) * D2_ + c4 * 4];
    f32x4 ha = *(const f32x4*)&hatt[b * D2_ + c4 * 4];
    f32x4 o;
    o.x = h.x * pm * ha.x; o.y = h.y * pm * ha.y;
    o.z = h.z * pm * ha.z; o.w = h.w * pm * ha.w;
    *(f32x4*)&G[((size_t)b * TP + i) * (4 * D2_) + 3 * D2_ + c4 * 4] = o;
  }
}

extern "C" void kernel_launch(void* const* d_in, const int* in_sizes, int n_in,
                              void* d_out, int out_size, void* d_ws, size_t ws_size,
                              hipStream_t stream) {
  const float* H  = (const float*)d_in[0];
  const float* U  = (const float*)d_in[1];
  const float* w  = (const float*)d_in[2];
  const int*   mp = (const int*)d_in[3];
  const int*   mq = (const int*)d_in[4];
  float* G = (float*)d_out;

  float* ws      = (float*)d_ws;
  float* udot    = ws;                       // 8192
  float* Smax    = udot + B_ * TQ;           // 65536
  float* Mb      = Smax + B_ * TP;           // 16
  float* Lb      = Mb + B_;                  // 16
  float* hatt    = Lb + B_;                  // 4096
  float* partial = hatt + B_ * D2_;          // 131072

  k_prep<<<dim3(NJT, B_), 256, 0, stream>>>(U, w, mq, G, udot);
  k_main<<<dim3(TP / TI, B_), 256, 0, stream>>>(H, w, mp, mq, udot, Smax, G);
  k_smax_reduce<<<dim3(B_), 256, 0, stream>>>(Smax, mp, Mb, Lb);
  k_hatt<<<dim3(32, B_), 256, 0, stream>>>(H, Smax, mp, Mb, Lb, partial);
  k_hatt_sum<<<dim3(B_), 256, 0, stream>>>(partial, hatt);
  k_g3<<<dim3(2048), 256, 0, stream>>>(H, mp, hatt, G);
}

// Round 3
// 231.986 us; speedup vs baseline: 1.7576x; 1.7576x over previous
//
#include <hip/hip_runtime.h>
#include <hip/hip_bf16.h>
#include <cstdint>

#define B_  16
#define TP  4096
#define TQ  512
#define D2_ 256
#define TI 64
#define TJ 32
#define NJT (TQ / TJ)   // 16

typedef _Float16 f16x8 __attribute__((ext_vector_type(8)));
typedef _Float16 f16x4 __attribute__((ext_vector_type(4)));
typedef float    f32x4 __attribute__((ext_vector_type(4)));

// ---- fragment blob stash: G slice-3 (last 1KB of each 4KB row) of rows 0..8191 ----
// frag (b,jt,f) occupies G row (b*NJT+jt)*32 + f; lane's 16B at f16 offset 1536 + lane*8.
// k_main writes only slices 0..2 (bytes 0..3071) of G rows, so blob bytes are untouched
// until k_g3 (launched after k_main) overwrites slice 3 with final output.
__device__ __forceinline__ _Float16* frag_wptr(float* G, int b, int jt, int f, int lane) {
  return (_Float16*)G + ((size_t)((b * NJT + jt) * 32 + f)) * 2048 + 1536 + lane * 8;
}

// ---------------- kernel 0: build f16 B-fragments + udot ----------------
__global__ __launch_bounds__(256) void k_prep(const float* __restrict__ U,
                                              const float* __restrict__ w,
                                              const int* __restrict__ mq,
                                              float* __restrict__ G,
                                              float* __restrict__ udot) {
  __shared__ _Float16 T[TJ][264];
  const int b = blockIdx.y, jt = blockIdx.x;
  const int tid = threadIdx.x, lane = tid & 63, wv = tid >> 6;
  const int l15 = lane & 15, g = lane >> 4;

  // stage Um tile (32 x 256) as f16
#pragma unroll
  for (int it = 0; it < 8; ++it) {
    int chunk = it * 256 + tid;             // 2048 chunks of 4 floats
    int r = chunk >> 6, c = (chunk & 63) * 4;
    int row = b * TQ + jt * TJ + r;
    float qmv = (float)mq[row];
    f32x4 u = *(const f32x4*)&U[(size_t)row * D2_ + c];
    f16x4 v;
    v[0] = (_Float16)(u.x * qmv); v[1] = (_Float16)(u.y * qmv);
    v[2] = (_Float16)(u.z * qmv); v[3] = (_Float16)(u.w * qmv);
    *(f16x4*)&T[r][c] = v;
  }
  __syncthreads();

  // udot: thread (r = tid>>3, s = tid&7) sums 32 elems, reduce over s
  {
    int r = tid >> 3, s = tid & 7;
    float p = 0.f;
#pragma unroll
    for (int e = 0; e < 32; ++e) p += (float)T[r][s * 32 + e] * w[D2_ + s * 32 + e];
    p += __shfl_xor(p, 1); p += __shfl_xor(p, 2); p += __shfl_xor(p, 4);
    if (s == 0) udot[b * TQ + jt * TJ + r] = p;
  }

  // fragments: wave wv writes frags f = wv*8 + q (wave-uniform branch)
#pragma unroll
  for (int q = 0; q < 8; ++q) {
    int f = wv * 8 + q;
    f16x8 v;
    if (f < 16) {
      // S-step B-frag: B[k=ks*32+g*8+e][j=t*16+l15] = U[j][k]
      int t = f >> 3, ks = f & 7;
      v = *(const f16x8*)&T[t * 16 + l15][ks * 32 + g * 8];
    } else {
      // PV B-frag: B[k=j=g*8+e][c=n*16+l15] = U[j][c]
      int n = f - 16;
#pragma unroll
      for (int e = 0; e < 8; ++e) v[e] = T[g * 8 + e][n * 16 + l15];
    }
    *(f16x8*)frag_wptr(G, b, jt, f, lane) = v;
  }
}

// ---------------- kernel 1: flash S/softmax/PV, no in-loop barriers ----------------
__global__ __launch_bounds__(512, 4) void k_main(
    const float* __restrict__ H, const float* __restrict__ w,
    const int* __restrict__ mp, const int* __restrict__ mq,
    const float* __restrict__ udot,
    float* __restrict__ SmaxOut, float* __restrict__ G) {

  __shared__ char smem[44544];
  _Float16 (*A4)[16][264] = (_Float16(*)[16][264])smem;            // 4 pairs x 16 x 264 f16 = 33792 B
  _Float16 (*P)[16][40]   = (_Float16(*)[16][40])(smem + 33792);   // 8 waves x 16 x 40 f16 = 10240 B
  float* hd_s = (float*)(smem + 33792 + 10240);                    // 64 f32
  _Float16 (*Uatt)[264] = (_Float16(*)[264])smem;                  // epilogue reuse: 64 x 264 f16

  const int b = blockIdx.y, i0 = blockIdx.x * TI;
  const int tid = threadIdx.x, lane = tid & 63, wv = tid >> 6;
  const int l15 = lane & 15, g = lane >> 4;
  const int pr = wv >> 1;        // pair 0..3: rows pr*16..pr*16+15
  const int h  = wv & 1;         // c-half: cols h*128..h*128+127

  // ---- prologue: pair-leader stages A = f16(Hm*w_hu) to LDS, hdot to LDS ----
  if (h == 0) {
    const int rowg = i0 + pr * 16 + l15;
    const float* Hrow = H + ((size_t)b * TP + rowg) * D2_;
    const float pmr = (float)mp[b * TP + rowg];
    float hp = 0.f;
#pragma unroll
    for (int ks = 0; ks < 8; ++ks) {
      int c0 = ks * 32 + g * 8;
      f32x4 h0 = *(const f32x4*)&Hrow[c0];
      f32x4 h1 = *(const f32x4*)&Hrow[c0 + 4];
      f32x4 wh0 = *(const f32x4*)&w[c0];
      f32x4 wh1 = *(const f32x4*)&w[c0 + 4];
      f32x4 wu0 = *(const f32x4*)&w[2 * D2_ + c0];
      f32x4 wu1 = *(const f32x4*)&w[2 * D2_ + c0 + 4];
      h0 *= pmr; h1 *= pmr;
      f16x8 a;
      a[0] = (_Float16)(h0.x * wu0.x); a[1] = (_Float16)(h0.y * wu0.y);
      a[2] = (_Float16)(h0.z * wu0.z); a[3] = (_Float16)(h0.w * wu0.w);
      a[4] = (_Float16)(h1.x * wu1.x); a[5] = (_Float16)(h1.y * wu1.y);
      a[6] = (_Float16)(h1.z * wu1.z); a[7] = (_Float16)(h1.w * wu1.w);
      *(f16x8*)&A4[pr][l15][c0] = a;
      hp += h0.x * wh0.x + h0.y * wh0.y + h0.z * wh0.z + h0.w * wh0.w
          + h1.x * wh1.x + h1.y * wh1.y + h1.z * wh1.z + h1.w * wh1.w;
    }
    hp += __shfl_xor(hp, 16);
    hp += __shfl_xor(hp, 32);
    if (g == 0) hd_s[pr * 16 + l15] = hp;
  }
  __syncthreads();   // only barrier before epilogue

  float hd[4];
#pragma unroll
  for (int reg = 0; reg < 4; ++reg) hd[reg] = hd_s[pr * 16 + g * 4 + reg];

  f32x4 Oacc[8];
#pragma unroll
  for (int n = 0; n < 8; ++n) Oacc[n] = {0.f, 0.f, 0.f, 0.f};
  float m_r[4] = {-1e30f, -1e30f, -1e30f, -1e30f};
  float l_r[4] = {0.f, 0.f, 0.f, 0.f};

  const _Float16* Gf = (const _Float16*)G;

  for (int jt = 0; jt < NJT; ++jt) {
    const _Float16* fb = Gf + ((size_t)((b * NJT + jt) * 32)) * 2048 + 1536 + lane * 8;

    // ---- S: 16 rows x 32 cols ----
    f32x4 Sacc[2];
    Sacc[0] = {0.f, 0.f, 0.f, 0.f}; Sacc[1] = {0.f, 0.f, 0.f, 0.f};
#pragma unroll
    for (int ks = 0; ks < 8; ++ks) {
      f16x8 af = *(const f16x8*)&A4[pr][l15][ks * 32 + g * 8];
      f16x8 b0 = *(const f16x8*)(fb + (size_t)ks * 2048);
      f16x8 b1 = *(const f16x8*)(fb + (size_t)(8 + ks) * 2048);
      Sacc[0] = __builtin_amdgcn_mfma_f32_16x16x32_f16(af, b0, Sacc[0], 0, 0, 0);
      Sacc[1] = __builtin_amdgcn_mfma_f32_16x16x32_f16(af, b1, Sacc[1], 0, 0, 0);
    }

    // ---- bias + online softmax (C layout: row=g*4+reg, col=t*16+l15) ----
    float ud[2], qv[2];
#pragma unroll
    for (int t = 0; t < 2; ++t) {
      ud[t] = udot[b * TQ + jt * TJ + t * 16 + l15];
      qv[t] = (float)mq[b * TQ + jt * TJ + t * 16 + l15];
    }
    float tmax[4] = {-1e30f, -1e30f, -1e30f, -1e30f};
#pragma unroll
    for (int t = 0; t < 2; ++t)
#pragma unroll
      for (int reg = 0; reg < 4; ++reg) {
        float v = Sacc[t][reg] + hd[reg] + ud[t];
        Sacc[t][reg] = v;
        tmax[reg] = fmaxf(tmax[reg], v);    // raw max, mask NOT applied (matches ref)
      }
#pragma unroll
    for (int o = 1; o < 16; o <<= 1)
#pragma unroll
      for (int reg = 0; reg < 4; ++reg)
        tmax[reg] = fmaxf(tmax[reg], __shfl_xor(tmax[reg], o));

    float scale[4], psum[4] = {0.f, 0.f, 0.f, 0.f};
#pragma unroll
    for (int reg = 0; reg < 4; ++reg) {
      float mn = fmaxf(m_r[reg], tmax[reg]);
      scale[reg] = __expf(m_r[reg] - mn);
      m_r[reg] = mn;
      l_r[reg] *= scale[reg];
    }
#pragma unroll
    for (int n = 0; n < 8; ++n)
#pragma unroll
      for (int reg = 0; reg < 4; ++reg)
        Oacc[n][reg] *= scale[reg];

#pragma unroll
    for (int t = 0; t < 2; ++t)
#pragma unroll
      for (int reg = 0; reg < 4; ++reg) {
        float p = qv[t] * __expf(Sacc[t][reg] - m_r[reg]);
        psum[reg] += p;
        P[wv][g * 4 + reg][t * 16 + l15] = (_Float16)p;  // per-wave private
      }
#pragma unroll
    for (int o = 1; o < 16; o <<= 1)
#pragma unroll
      for (int reg = 0; reg < 4; ++reg)
        psum[reg] += __shfl_xor(psum[reg], o);
#pragma unroll
    for (int reg = 0; reg < 4; ++reg) l_r[reg] += psum[reg];

    // ---- PV: Oacc(16 x 128-half) += P(16x32) @ U(32 x c-half) ----
    f16x8 pf = *(const f16x8*)&P[wv][l15][g * 8];
#pragma unroll
    for (int n = 0; n < 8; ++n) {
      f16x8 uf = *(const f16x8*)(fb + (size_t)(16 + h * 8 + n) * 2048);
      Oacc[n] = __builtin_amdgcn_mfma_f32_16x16x32_f16(pf, uf, Oacc[n], 0, 0, 0);
    }
  }

  // ---- Smax out (raw row max), by pair leaders ----
  if (h == 0 && l15 == 0) {
#pragma unroll
    for (int reg = 0; reg < 4; ++reg)
      SmaxOut[b * TP + i0 + pr * 16 + g * 4 + reg] = m_r[reg];
  }

  // ---- epilogue: normalize, park U_att (f16) in LDS, coalesced G writes ----
  float inv_l[4];
#pragma unroll
  for (int reg = 0; reg < 4; ++reg) inv_l[reg] = 1.0f / l_r[reg];
  __syncthreads();   // everyone done with A4/P before Uatt overwrites
#pragma unroll
  for (int n = 0; n < 8; ++n)
#pragma unroll
    for (int reg = 0; reg < 4; ++reg)
      Uatt[pr * 16 + g * 4 + reg][h * 128 + n * 16 + l15] =
          (_Float16)(Oacc[n][reg] * inv_l[reg]);
  __syncthreads();

  const int* pmb = mp + b * TP + i0;
#pragma unroll
  for (int it = 0; it < 8; ++it) {
    int idx4 = it * 512 + tid;
    int r = idx4 >> 6, c = (idx4 & 63) * 4;
    float pm = (float)pmb[r];
    f32x4 hv = *(const f32x4*)&H[((size_t)b * TP + i0 + r) * D2_ + c];
    hv *= pm;                                   // Hm
    f16x4 u4 = *(const f16x4*)&Uatt[r][c];
    f32x4 u; u.x = (float)u4[0]; u.y = (float)u4[1]; u.z = (float)u4[2]; u.w = (float)u4[3];
    size_t ro = ((size_t)b * TP + i0 + r) * (4 * D2_);
    *(f32x4*)&G[ro + c] = hv;                   // slice 0: Hm
    f32x4 up = u * pm;
    *(f32x4*)&G[ro + D2_ + c] = up;             // slice 1: U_att * pm
    f32x4 hu; hu.x = hv.x * u.x; hu.y = hv.y * u.y; hu.z = hv.z * u.z; hu.w = hv.w * u.w;
    *(f32x4*)&G[ro + 2 * D2_ + c] = hu;         // slice 2: Hm * U_att
  }
}

// ---------------- kernel 3a: per-batch max & sum-exp over Smax ----------------
__global__ __launch_bounds__(256) void k_smax_reduce(const float* __restrict__ Smax,
    const int* __restrict__ mp, float* __restrict__ Mb, float* __restrict__ Lb) {
  int b = blockIdx.x;
  int tid = threadIdx.x;
  const float* S = Smax + b * TP;
  const int* pm = mp + b * TP;
  __shared__ float redm[4], reds[4];
  float mx = -1e30f;
  for (int i = tid; i < TP; i += 256) mx = fmaxf(mx, S[i]);
#pragma unroll
  for (int o = 32; o; o >>= 1) mx = fmaxf(mx, __shfl_down(mx, o));
  if ((tid & 63) == 0) redm[tid >> 6] = mx;
  __syncthreads();
  mx = fmaxf(fmaxf(redm[0], redm[1]), fmaxf(redm[2], redm[3]));
  float s = 0.f;
  for (int i = tid; i < TP; i += 256) s += pm[i] ? __expf(S[i] - mx) : 0.f;
#pragma unroll
  for (int o = 32; o; o >>= 1) s += __shfl_down(s, o);
  if ((tid & 63) == 0) reds[tid >> 6] = s;
  __syncthreads();
  if (tid == 0) { Mb[b] = mx; Lb[b] = reds[0] + reds[1] + reds[2] + reds[3]; }
}

// ---------------- kernel 3b: partial h_att (deterministic) ----------------
__global__ __launch_bounds__(256) void k_hatt(const float* __restrict__ H,
    const float* __restrict__ Smax, const int* __restrict__ mp,
    const float* __restrict__ Mb, const float* __restrict__ Lb,
    float* __restrict__ partial) {
  int b = blockIdx.y;
  int chunk = blockIdx.x;
  int c = threadIdx.x;
  float mx = Mb[b];
  float inv = 1.0f / Lb[b];
  float acc = 0.f;
  int i0 = chunk * 128;
  for (int ii = 0; ii < 128; ++ii) {
    int i = i0 + ii;
    float sm = Smax[b * TP + i];
    float wgt = mp[b * TP + i] ? __expf(sm - mx) * inv : 0.f;
    acc += wgt * H[((size_t)b * TP + i) * D2_ + c];
  }
  partial[((size_t)b * 32 + chunk) * D2_ + c] = acc;
}

// ---------------- kernel 3c: sum partials -> h_att ----------------
__global__ __launch_bounds__(256) void k_hatt_sum(const float* __restrict__ partial,
                                                  float* __restrict__ hatt) {
  int b = blockIdx.x;
  int c = threadIdx.x;
  float s = 0.f;
#pragma unroll
  for (int k = 0; k < 32; ++k) s += partial[((size_t)b * 32 + k) * D2_ + c];
  hatt[b * D2_ + c] = s;
}

// ---------------- kernel 4: G slice 3 = Hm * h_att ----------------
__global__ __launch_bounds__(256) void k_g3(const float* __restrict__ H,
    const int* __restrict__ mp, const float* __restrict__ hatt,
    float* __restrict__ G) {
  const int total = B_ * TP * (D2_ / 4);
  for (int idx = blockIdx.x * 256 + threadIdx.x; idx < total; idx += gridDim.x * 256) {
    int c4 = idx & 63;
    int i = (idx >> 6) & (TP - 1);
    int b = idx >> 18;
    float pm = (float)mp[b * TP + i];
    f32x4 h = *(const f32x4*)&H[((size_t)b * TP + i) * D2_ + c4 * 4];
    f32x4 ha = *(const f32x4*)&hatt[b * D2_ + c4 * 4];
    f32x4 o;
    o.x = h.x * pm * ha.x; o.y = h.y * pm * ha.y;
    o.z = h.z * pm * ha.z; o.w = h.w * pm * ha.w;
    *(f32x4*)&G[((size_t)b * TP + i) * (4 * D2_) + 3 * D2_ + c4 * 4] = o;
  }
}

extern "C" void kernel_launch(void* const* d_in, const int* in_sizes, int n_in,
                              void* d_out, int out_size, void* d_ws, size_t ws_size,
                              hipStream_t stream) {
  const float* H  = (const float*)d_in[0];
  const float* U  = (const float*)d_in[1];
  const float* w  = (const float*)d_in[2];
  const int*   mp = (const int*)d_in[3];
  const int*   mq = (const int*)d_in[4];
  float* G = (float*)d_out;

  float* ws      = (float*)d_ws;
  float* udot    = ws;                       // 8192
  float* Smax    = udot + B_ * TQ;           // 65536
  float* Mb      = Smax + B_ * TP;           // 16
  float* Lb      = Mb + B_;                  // 16
  float* hatt    = Lb + B_;                  // 4096
  float* partial = hatt + B_ * D2_;          // 131072

  k_prep<<<dim3(NJT, B_), 256, 0, stream>>>(U, w, mq, G, udot);
  k_main<<<dim3(TP / TI, B_), 512, 0, stream>>>(H, w, mp, mq, udot, Smax, G);
  k_smax_reduce<<<dim3(B_), 256, 0, stream>>>(Smax, mp, Mb, Lb);
  k_hatt<<<dim3(32, B_), 256, 0, stream>>>(H, Smax, mp, Mb, Lb, partial);
  k_hatt_sum<<<dim3(B_), 256, 0, stream>>>(partial, hatt);
  k_g3<<<dim3(2048), 256, 0, stream>>>(H, mp, hatt, G);
}